// Round 1
// 1067.243 us; speedup vs baseline: 1.3493x; 1.3493x over previous
//
#include <hip/hip_runtime.h>
#include <hip/hip_bf16.h>

#define N_USERS   50000
#define N_ITEMS   100000
#define N_NODES   150000
#define DIM       64
#define N_INTENTS 128
#define N_EDGES   3000000
#define PSHIFT    9                         // 512 rows per partition
#define PROWS     (1 << PSHIFT)
#define NPART     ((N_NODES + PROWS - 1) >> PSHIFT)   // 293
#define CHUNK     16384                     // edges per binning block
#define NCHB      ((N_EDGES + CHUNK - 1) / CHUNK)     // 184

typedef __attribute__((ext_vector_type(8))) short short8v;  // 8 bf16 (4 VGPRs)
typedef __attribute__((ext_vector_type(4))) float f32x4;

static __device__ __forceinline__ float wsum64(float v){
#pragma unroll
  for (int m = 32; m >= 1; m >>= 1) v += __shfl_xor(v, m, 64);
  return v;
}
static __device__ __forceinline__ float wmax64(float v){
#pragma unroll
  for (int m = 32; m >= 1; m >>= 1) v = fmaxf(v, __shfl_xor(v, m, 64));
  return v;
}

// ---- DPP 16-lane row reduction (full-rate VALU)
template<int CTRL>
static __device__ __forceinline__ float dpp_ror_add(float x){
  int t = __builtin_amdgcn_update_dpp(0, __builtin_bit_cast(int, x),
                                      CTRL, 0xF, 0xF, true);
  return x + __builtin_bit_cast(float, t);
}
static __device__ __forceinline__ float row16_allsum(float x){
  x = dpp_ror_add<0x128>(x);  // row_ror:8
  x = dpp_ror_add<0x124>(x);  // row_ror:4
  x = dpp_ror_add<0x122>(x);  // row_ror:2
  x = dpp_ror_add<0x121>(x);  // row_ror:1
  return x;
}
template<int CTRL>
static __device__ __forceinline__ float dpp_ror_max(float x){
  int t = __builtin_amdgcn_update_dpp(0, __builtin_bit_cast(int, x),
                                      CTRL, 0xF, 0xF, true);
  return fmaxf(x, __builtin_bit_cast(float, t));
}
static __device__ __forceinline__ float row16_allmax(float x){
  x = dpp_ror_max<0x128>(x);
  x = dpp_ror_max<0x124>(x);
  x = dpp_ror_max<0x122>(x);
  x = dpp_ror_max<0x121>(x);
  return x;
}

// bf16 pack/unpack
static __device__ __forceinline__ unsigned short f2bf(float x){
  __hip_bfloat16 h = __float2bfloat16(x);
  return __builtin_bit_cast(unsigned short, h);
}
static __device__ __forceinline__ float bf_lo(unsigned int v){
  return __builtin_bit_cast(float, v << 16);
}
static __device__ __forceinline__ float bf_hi(unsigned int v){
  return __builtin_bit_cast(float, v & 0xFFFF0000u);
}
static __device__ __forceinline__ float bfval(unsigned short h){
  return __builtin_bit_cast(float, (unsigned int)h << 16);
}
// hi/lo bf16 split: x ~= bf(hi) + bf(lo), rel err ~2^-17 (fp32-fidelity for MFMA)
static __device__ __forceinline__ void split2(float x, unsigned short& hi,
                                              unsigned short& lo){
  hi = f2bf(x);
  lo = f2bf(x - bfval(hi));
}

// emb = concat(user_emb, item_emb); acc(=d_out) = emb; embb = bf16(emb)
__global__ void k_init(const float* __restrict__ ue, const float* __restrict__ ie,
                       float* __restrict__ emb, float* __restrict__ acc,
                       unsigned short* __restrict__ embb){
  int i = blockIdx.x * 256 + threadIdx.x;
  if (i >= N_NODES * DIM) return;
  float v = (i < N_USERS * DIM) ? ue[i] : ie[i - N_USERS * DIM];
  emb[i] = v; acc[i] = v; embb[i] = f2bf(v);
}

__global__ void k_deg(const int* __restrict__ h, int* __restrict__ deg){
  int e = blockIdx.x * 256 + threadIdx.x;
  if (e < N_EDGES) atomicAdd(&deg[h[e]], 1);
}

__global__ void k_scan1(const int* __restrict__ deg, int* __restrict__ tmp,
                        int* __restrict__ aux){
  __shared__ int s[256];
  int t = threadIdx.x, i = blockIdx.x * 256 + t;
  int v = (i < N_NODES) ? deg[i] : 0;
  s[t] = v; __syncthreads();
  for (int off = 1; off < 256; off <<= 1){
    int x = (t >= off) ? s[t - off] : 0;
    __syncthreads();
    s[t] += x;
    __syncthreads();
  }
  if (i < N_NODES) tmp[i] = s[t];
  if (t == 255) aux[blockIdx.x] = s[255];
}

__global__ __launch_bounds__(1024) void k_scan2(int* __restrict__ aux, int n){
  __shared__ int s[1024];
  int t = threadIdx.x;
  int v = (t < n) ? aux[t] : 0;
  s[t] = v; __syncthreads();
  for (int off = 1; off < 1024; off <<= 1){
    int x = (t >= off) ? s[t - off] : 0;
    __syncthreads();
    s[t] += x;
    __syncthreads();
  }
  if (t < n) aux[t] = s[t] - v;   // exclusive
}

__global__ void k_rowptr(const int* __restrict__ tmp, const int* __restrict__ deg,
                         const int* __restrict__ aux, int* __restrict__ rp,
                         float* __restrict__ dis, int* __restrict__ gcur){
  int i = blockIdx.x * 256 + threadIdx.x;
  if (i < N_NODES){
    int v = aux[i >> 8] + tmp[i] - deg[i];
    rp[i] = v;
    int d = deg[i];
    dis[i] = (d > 0) ? (1.f / sqrtf((float)d)) : 0.f;
    if ((i & (PROWS - 1)) == 0) gcur[i >> PSHIFT] = v;  // partition append cursor
  }
  if (i == 0) rp[N_NODES] = N_EDGES;
}

// Counting-sort pass 1: per-block LDS histogram over 293 partitions, ONE
// global reservation per (block,partition), then scatter into block-exclusive
// contiguous runs.
__global__ __launch_bounds__(256) void k_part1(const int* __restrict__ h,
                                               const int* __restrict__ t,
                                               int* __restrict__ gcur,
                                               unsigned int* __restrict__ stg){
  __shared__ int hist[NPART];
  __shared__ int base[NPART];
  __shared__ int cnt2[NPART];
  int tid = threadIdx.x;
  int s = blockIdx.x * CHUNK;
  int e = min(s + CHUNK, N_EDGES);
  for (int p = tid; p < NPART; p += 256){ hist[p] = 0; cnt2[p] = 0; }
  __syncthreads();
  for (int i = s + tid; i < e; i += 256)
    atomicAdd(&hist[h[i] >> PSHIFT], 1);
  __syncthreads();
  for (int p = tid; p < NPART; p += 256){
    int c = hist[p];
    base[p] = c ? atomicAdd(&gcur[p], c) : 0;
  }
  __syncthreads();
  for (int i = s + tid; i < e; i += 256){
    int hh = h[i];
    int part = hh >> PSHIFT;
    int pos = base[part] + atomicAdd(&cnt2[part], 1);
    stg[pos] = ((unsigned)t[i] << PSHIFT) | (unsigned)(hh & (PROWS - 1));
  }
}

// Counting-sort pass 2: one block per partition.
__global__ __launch_bounds__(256) void k_part2(const int* __restrict__ rp,
                                               const unsigned int* __restrict__ stg,
                                               int* __restrict__ t_csr){
  __shared__ int cur[PROWS];
  int b = blockIdx.x, tid = threadIdx.x;
  int row0 = b << PSHIFT;
  int rows = min(PROWS, N_NODES - row0);
  for (int i = tid; i < rows; i += 256) cur[i] = rp[row0 + i];
  __syncthreads();
  int s = rp[row0], e = rp[row0 + rows];
  for (int i = s + tid; i < e; i += 256){
    unsigned int v = stg[i];
    int pos = atomicAdd(&cur[v & (PROWS - 1)], 1);
    t_csr[pos] = (int)(v >> PSHIFT);
  }
}

// gnn[n] = dis[n] * sum_e dis[t_e] * emb[t_e], gathering bf16 embb (128B/edge)
__global__ void k_spmm_gnn(const int* __restrict__ rp, const int* __restrict__ t_csr,
                           const float* __restrict__ dis,
                           const uint2* __restrict__ embb2,
                           float* __restrict__ gnn, unsigned short* __restrict__ hgig_s){
  int w = (blockIdx.x * 256 + threadIdx.x) >> 6;
  int lane = threadIdx.x & 63;
  if (w >= N_NODES) return;
  int slot = lane >> 4, sub = lane & 15;
  int s = rp[w], e = rp[w + 1];
  float4 a = make_float4(0.f, 0.f, 0.f, 0.f);
  for (int i = s + slot; i < e; i += 4){
    int t = t_csr[i];
    float wt = dis[t];
    uint2 ev = embb2[t * 16 + sub];
    a.x = fmaf(wt, bf_lo(ev.x), a.x);
    a.y = fmaf(wt, bf_hi(ev.x), a.y);
    a.z = fmaf(wt, bf_lo(ev.y), a.z);
    a.w = fmaf(wt, bf_hi(ev.y), a.w);
  }
#pragma unroll
  for (int m = 16; m <= 32; m <<= 1){
    a.x += __shfl_xor(a.x, m, 64);
    a.y += __shfl_xor(a.y, m, 64);
    a.z += __shfl_xor(a.z, m, 64);
    a.w += __shfl_xor(a.w, m, 64);
  }
  float dw = dis[w];
  float4 gv = make_float4(dw * a.x, dw * a.y, dw * a.z, dw * a.w);
  float sq = gv.x * gv.x + gv.y * gv.y + gv.z * gv.z + gv.w * gv.w;
  float nrm = row16_allsum(sq);
  float invn = 1.f / fmaxf(sqrtf(nrm), 1e-8f);
  if (slot == 0){
    ((float4*)gnn)[w * 16 + sub] = gv;
    int base = (w * DIM + 4 * sub) * 2;
    hgig_s[base]     = f2bf(gv.x * invn);
    hgig_s[base + 2] = f2bf(gv.y * invn);
    hgig_s[base + 4] = f2bf(gv.z * invn);
    hgig_s[base + 6] = f2bf(gv.w * invn);
  }
}

// ---------------------------------------------------------------------------
// One-shot W preparation for the MFMA intent kernel.
// Per W (user=block0, item=block1), seg layout in shorts:
//   [0,8192)      w1 B-frags hi: frag f=nt*2+ks, lane, e -> W[8*(l>>4)+e+32*ks][16*nt+(l&15)]
//   [8192,16384)  w1 B-frags lo
//   [16384,24576) W row-major bf16 hi  (B-frags of W^T read contiguously from here)
//   [24576,32768) W row-major bf16 lo
// ---------------------------------------------------------------------------
__global__ void k_wprep(const float* __restrict__ wu, const float* __restrict__ wi,
                        unsigned short* __restrict__ wbuf){
  const float* W = blockIdx.x ? wi : wu;
  unsigned short* seg = wbuf + blockIdx.x * 32768;
  int tid = threadIdx.x;
  for (int i = tid; i < DIM * N_INTENTS; i += 256){
    unsigned short h, l; split2(W[i], h, l);
    seg[16384 + i] = h; seg[24576 + i] = l;
  }
  for (int idx = tid; idx < 16 * 64; idx += 256){
    int f = idx >> 6, lane = idx & 63;
    int nt = f >> 1, ks = f & 1, g = lane >> 4, c = lane & 15;
    int in = 16 * nt + c;
#pragma unroll
    for (int e = 0; e < 8; e++){
      int d = 8 * g + e + 32 * ks;
      unsigned short h, l; split2(W[d * N_INTENTS + in], h, l);
      seg[f * 512 + lane * 8 + e] = h;
      seg[8192 + f * 512 + lane * 8 + e] = l;
    }
  }
}

// ---------------------------------------------------------------------------
// MFMA intent kernel: out = softmax(emb @ W) @ W^T, bf16 out + L2-norm into
// hgig odd halves. One 16-node tile per wave; 4 waves/block; no barriers
// (LDS is wave-private). hi/lo bf16 split + 3-product MFMA ~= fp32 fidelity.
// mfma_f32_16x16x32_bf16 layouts (std CDNA): A[m=l&15][k=8*(l>>4)+e],
// B[k=8*(l>>4)+e][n=l&15], D[m=4*(l>>4)+r][n=l&15].
// ---------------------------------------------------------------------------
__global__ __launch_bounds__(256) void k_intent_mfma(
    const unsigned short* __restrict__ wseg, const float* __restrict__ emb,
    unsigned short* __restrict__ out_bf, unsigned short* __restrict__ hgig_s,
    int base_node, int count){
  __shared__ __align__(16) unsigned int Pl[4][2048];   // 8KB per wave: P hi|lo packed
  int wid = threadIdx.x >> 6, lane = threadIdx.x & 63;
  int tile = blockIdx.x * 4 + wid;
  if (tile * 16 >= count) return;
  int g = lane >> 4, c = lane & 15;

  // ---- A-frags of E (hi/lo), node row = tile*16 + c, dims 8g..8g+7 (+32 for ks=1)
  const float4* erow = (const float4*)(emb + (size_t)(base_node + tile * 16 + c) * DIM);
  float4 ea0 = erow[2 * g],     eb0 = erow[2 * g + 1];
  float4 ea1 = erow[8 + 2 * g], eb1 = erow[9 + 2 * g];
  short8v ehi[2], elo[2];
  {
    float xs[16] = {ea0.x, ea0.y, ea0.z, ea0.w, eb0.x, eb0.y, eb0.z, eb0.w,
                    ea1.x, ea1.y, ea1.z, ea1.w, eb1.x, eb1.y, eb1.z, eb1.w};
#pragma unroll
    for (int ksi = 0; ksi < 2; ksi++)
#pragma unroll
      for (int e = 0; e < 8; e++){
        unsigned short h, l; split2(xs[ksi * 8 + e], h, l);
        ehi[ksi][e] = (short)h; elo[ksi][e] = (short)l;
      }
  }

  // ---- matmul1: L = E @ W  (8 n-tiles of 16 intents, K=64 in 2 steps)
  const uint4* w1hi = (const uint4*)wseg;
  const uint4* w1lo = (const uint4*)(wseg + 8192);
  f32x4 acc1[8];
#pragma unroll
  for (int nt = 0; nt < 8; nt++){
    f32x4 a = {0.f, 0.f, 0.f, 0.f};
#pragma unroll
    for (int ks = 0; ks < 2; ks++){
      short8v wh = __builtin_bit_cast(short8v, w1hi[(nt * 2 + ks) * 64 + lane]);
      short8v wl = __builtin_bit_cast(short8v, w1lo[(nt * 2 + ks) * 64 + lane]);
      a = __builtin_amdgcn_mfma_f32_16x16x32_bf16(ehi[ks], wh, a, 0, 0, 0);
      a = __builtin_amdgcn_mfma_f32_16x16x32_bf16(elo[ks], wh, a, 0, 0, 0);
      a = __builtin_amdgcn_mfma_f32_16x16x32_bf16(ehi[ks], wl, a, 0, 0, 0);
    }
    acc1[nt] = a;
  }

  // ---- softmax per node (row r of D = node 4g+r; intents = 16*nt + c across
  // the 16-lane DPP row). Normalized P packed hi|lo into wave-private LDS,
  // XOR-swizzled so the stride-512B frag reads below are conflict-free.
  unsigned int* pw = &Pl[wid][0];
#pragma unroll
  for (int r = 0; r < 4; r++){
    float m = acc1[0][r];
#pragma unroll
    for (int nt = 1; nt < 8; nt++) m = fmaxf(m, acc1[nt][r]);
    m = row16_allmax(m);
    float p[8];
    float s = 0.f;
#pragma unroll
    for (int nt = 0; nt < 8; nt++){ p[nt] = __expf(acc1[nt][r] - m); s += p[nt]; }
    s = row16_allsum(s);
    float inv = 1.f / s;
    int node = 4 * g + r;
    int swz = (node & 7) << 2;
    int base = node * 128 + c;
#pragma unroll
    for (int nt = 0; nt < 8; nt++){
      float v = p[nt] * inv;
      unsigned short h, l; split2(v, h, l);
      pw[(base + 16 * nt) ^ swz] = (unsigned int)h | ((unsigned int)l << 16);
    }
  }

  // ---- A-frags of P for matmul2: node = c, intents 8g..8g+7 (+32*ks)
  const uint4* pr = (const uint4*)pw;
  short8v phf[4], plf[4];
  int sw = (c & 7) << 2;
#pragma unroll
  for (int ks = 0; ks < 4; ks++){
    int i0 = c * 128 + 8 * g + 32 * ks;
    uint4 ra = pr[(i0 ^ sw) >> 2];
    uint4 rb = pr[((i0 + 4) ^ sw) >> 2];
    unsigned int q[8] = {ra.x, ra.y, ra.z, ra.w, rb.x, rb.y, rb.z, rb.w};
#pragma unroll
    for (int e = 0; e < 8; e++){
      phf[ks][e] = (short)(q[e] & 0xFFFFu);
      plf[ks][e] = (short)(q[e] >> 16);
    }
  }

  // ---- matmul2: O = P @ W^T. B-frags of W^T are contiguous rows of
  // row-major bf16 W: row = 16*nt + c, cols 8g..8g+7 (+32*ks).
  const uint4* w2hi = (const uint4*)(wseg + 16384);
  const uint4* w2lo = (const uint4*)(wseg + 24576);
  f32x4 acc2[4];
#pragma unroll
  for (int nt = 0; nt < 4; nt++){
    f32x4 a = {0.f, 0.f, 0.f, 0.f};
#pragma unroll
    for (int ks = 0; ks < 4; ks++){
      int fi = (16 * nt + c) * 16 + ks * 4 + g;
      short8v wh = __builtin_bit_cast(short8v, w2hi[fi]);
      short8v wl = __builtin_bit_cast(short8v, w2lo[fi]);
      a = __builtin_amdgcn_mfma_f32_16x16x32_bf16(phf[ks], wh, a, 0, 0, 0);
      a = __builtin_amdgcn_mfma_f32_16x16x32_bf16(plf[ks], wh, a, 0, 0, 0);
      a = __builtin_amdgcn_mfma_f32_16x16x32_bf16(phf[ks], wl, a, 0, 0, 0);
    }
    acc2[nt] = a;
  }

  // ---- outputs: D[m=4g+r][n=c] -> node 4g+r, dim 16*nt + c.
  // Row L2-norm = in-lane sum over nt + row16 DPP sum (= 64 dims).
#pragma unroll
  for (int r = 0; r < 4; r++){
    float sq = 0.f;
#pragma unroll
    for (int nt = 0; nt < 4; nt++) sq = fmaf(acc2[nt][r], acc2[nt][r], sq);
    sq = row16_allsum(sq);
    float invn = 1.f / fmaxf(sqrtf(sq), 1e-8f);
    size_t gbase = (size_t)(base_node + tile * 16 + 4 * g + r) * DIM + c;
#pragma unroll
    for (int nt = 0; nt < 4; nt++){
      float v = acc2[nt][r];
      out_bf[gbase + 16 * nt] = f2bf(v);
      hgig_s[2 * (gbase + 16 * nt) + 1] = f2bf(v * invn);
    }
  }
}

// Fused adaptive passes + residual + acc + bf16 emb for next layer.
__global__ void k_adafuse(const int* __restrict__ rp, const int* __restrict__ t_csr,
                          const uint4* __restrict__ hgig4,
                          const uint2* __restrict__ inte_bf2,
                          const uint2* __restrict__ embb2,
                          const float* __restrict__ emb,
                          float* __restrict__ gnn_io, float* __restrict__ acc,
                          uint2* __restrict__ embb_next2){
  int w = (blockIdx.x * 256 + threadIdx.x) >> 6;
  int lane = threadIdx.x & 63;
  if (w >= N_NODES) return;
  int slot = lane >> 4, sub = lane & 15;
  uint4 hp = hgig4[w * 16 + sub];
  float hg0 = bf_lo(hp.x), hg1 = bf_lo(hp.y), hg2 = bf_lo(hp.z), hg3 = bf_lo(hp.w);
  float hi0 = bf_hi(hp.x), hi1 = bf_hi(hp.y), hi2 = bf_hi(hp.z), hi3 = bf_hi(hp.w);
  int s = rp[w], e = rp[w + 1];
  float4 s1 = make_float4(0.f, 0.f, 0.f, 0.f);
  float4 s2 = make_float4(0.f, 0.f, 0.f, 0.f);
  float r1 = 0.f, r2 = 0.f;
  for (int i = s + slot; i < e; i += 4){
    int t = t_csr[i];
    uint4 tp = hgig4[t * 16 + sub];
    uint2 ev = embb2[t * 16 + sub];
    float p = hg0 * bf_lo(tp.x) + hg1 * bf_lo(tp.y)
            + hg2 * bf_lo(tp.z) + hg3 * bf_lo(tp.w);
    float q = hi0 * bf_hi(tp.x) + hi1 * bf_hi(tp.y)
            + hi2 * bf_hi(tp.z) + hi3 * bf_hi(tp.w);
    p = row16_allsum(p);
    q = row16_allsum(q);
    float a1 = fmaf(p, 0.5f, 0.5f);
    float a2 = fmaf(q, 0.5f, 0.5f);
    r1 += a1; r2 += a2;
    float v0 = bf_lo(ev.x), v1 = bf_hi(ev.x), v2 = bf_lo(ev.y), v3 = bf_hi(ev.y);
    s1.x = fmaf(a1, v0, s1.x); s1.y = fmaf(a1, v1, s1.y);
    s1.z = fmaf(a1, v2, s1.z); s1.w = fmaf(a1, v3, s1.w);
    s2.x = fmaf(a2, v0, s2.x); s2.y = fmaf(a2, v1, s2.y);
    s2.z = fmaf(a2, v2, s2.z); s2.w = fmaf(a2, v3, s2.w);
  }
#pragma unroll
  for (int m = 16; m <= 32; m <<= 1){
    s1.x += __shfl_xor(s1.x, m, 64); s1.y += __shfl_xor(s1.y, m, 64);
    s1.z += __shfl_xor(s1.z, m, 64); s1.w += __shfl_xor(s1.w, m, 64);
    s2.x += __shfl_xor(s2.x, m, 64); s2.y += __shfl_xor(s2.y, m, 64);
    s2.z += __shfl_xor(s2.z, m, 64); s2.w += __shfl_xor(s2.w, m, 64);
    r1   += __shfl_xor(r1,   m, 64); r2   += __shfl_xor(r2,   m, 64);
  }
  float d1 = (r1 > 0.f) ? 1.f / r1 : 0.f;
  float d2 = (r2 > 0.f) ? 1.f / r2 : 0.f;
  if (slot == 0){
    int idx4 = w * 16 + sub;
    float4 g = ((float4*)gnn_io)[idx4];
    uint2 it = inte_bf2[idx4];
    float4 em = ((const float4*)emb)[idx4];
    float4 nv;
    nv.x = g.x + bf_lo(it.x) + em.x + d1 * s1.x + d2 * s2.x;
    nv.y = g.y + bf_hi(it.x) + em.y + d1 * s1.y + d2 * s2.y;
    nv.z = g.z + bf_lo(it.y) + em.z + d1 * s1.z + d2 * s2.z;
    nv.w = g.w + bf_hi(it.y) + em.w + d1 * s1.w + d2 * s2.w;
    ((float4*)gnn_io)[idx4] = nv;
    float4 ac = ((float4*)acc)[idx4];
    ac.x += nv.x; ac.y += nv.y; ac.z += nv.z; ac.w += nv.w;
    ((float4*)acc)[idx4] = ac;
    uint2 ob;
    ob.x = (unsigned)f2bf(nv.x) | ((unsigned)f2bf(nv.y) << 16);
    ob.y = (unsigned)f2bf(nv.z) | ((unsigned)f2bf(nv.w) << 16);
    embb_next2[idx4] = ob;   // bf16 emb for next layer (other buffer: no race)
  }
}

extern "C" void kernel_launch(void* const* d_in, const int* in_sizes, int n_in,
                              void* d_out, int out_size, void* d_ws, size_t ws_size,
                              hipStream_t stream){
  const float* ue = (const float*)d_in[0];
  const float* ie = (const float*)d_in[1];
  const float* wu = (const float*)d_in[2];
  const float* wi = (const float*)d_in[3];
  const int* all_h = (const int*)d_in[4];
  const int* all_t = (const int*)d_in[5];
  float* acc = (float*)d_out;

  char* p = (char*)d_ws;
  auto take = [&](size_t bytes)->char*{
    char* r = p; p += (bytes + 255) & ~size_t(255); return r;
  };
  float*  embA  = (float*)take(sizeof(float) * N_NODES * DIM);
  float*  embB  = (float*)take(sizeof(float) * N_NODES * DIM);
  unsigned int* hgig = (unsigned int*)take(sizeof(unsigned int) * N_NODES * DIM);
  unsigned short* inte_bf = (unsigned short*)take(sizeof(short) * N_NODES * DIM);
  unsigned short* embbA   = (unsigned short*)take(sizeof(short) * N_NODES * DIM);
  unsigned short* embbB   = (unsigned short*)take(sizeof(short) * N_NODES * DIM);
  unsigned short* wbuf    = (unsigned short*)take(sizeof(short) * 2 * 32768);
  int*    t_csr = (int*)take(sizeof(int) * N_EDGES);
  float*  dis   = (float*)take(sizeof(float) * N_NODES);
  int*    deg   = (int*)take(sizeof(int) * N_NODES);
  int*    tmp   = (int*)take(sizeof(int) * N_NODES);
  int*    aux   = (int*)take(sizeof(int) * 1024);
  int*    rp    = (int*)take(sizeof(int) * (N_NODES + 1));
  int*    gcur  = (int*)take(sizeof(int) * NPART);
  if ((size_t)(p - (char*)d_ws) > ws_size) return;
  // staging (12 MB) aliases hgig (38.4 MB): only live before the layer loop
  unsigned int* stg = hgig;

  const int ELEM_B  = (N_NODES * DIM + 255) / 256;
  const int NODEW_B = (N_NODES * 64 + 255) / 256;
  const int EDGE_B  = (N_EDGES + 255) / 256;
  const int NODE_B  = (N_NODES + 255) / 256;

  hipMemsetAsync(deg, 0, sizeof(int) * N_NODES, stream);
  k_init<<<ELEM_B, 256, 0, stream>>>(ue, ie, embA, acc, embbA);
  k_wprep<<<2, 256, 0, stream>>>(wu, wi, wbuf);
  k_deg<<<EDGE_B, 256, 0, stream>>>(all_h, deg);
  k_scan1<<<NODE_B, 256, 0, stream>>>(deg, tmp, aux);
  k_scan2<<<1, 1024, 0, stream>>>(aux, NODE_B);
  k_rowptr<<<NODE_B, 256, 0, stream>>>(tmp, deg, aux, rp, dis, gcur);
  k_part1<<<NCHB, 256, 0, stream>>>(all_h, all_t, gcur, stg);
  k_part2<<<NPART, 256, 0, stream>>>(rp, stg, t_csr);

  const int UT_B = ((N_USERS / 16) + 3) / 4;   // 3125 tiles -> 782 blocks
  const int IT_B = ((N_ITEMS / 16) + 3) / 4;   // 6250 tiles -> 1563 blocks

  float* eA = embA;
  float* eB = embB;
  unsigned short* ebA = embbA;  // bf16 of current emb
  unsigned short* ebB = embbB;
  for (int layer = 0; layer < 2; layer++){
    k_spmm_gnn<<<NODEW_B, 256, 0, stream>>>(rp, t_csr, dis, (const uint2*)ebA,
                                            eB, (unsigned short*)hgig);
    k_intent_mfma<<<UT_B, 256, 0, stream>>>(wbuf, eA, inte_bf,
                                            (unsigned short*)hgig, 0, N_USERS);
    k_intent_mfma<<<IT_B, 256, 0, stream>>>(wbuf + 32768, eA, inte_bf,
                                            (unsigned short*)hgig, N_USERS, N_ITEMS);
    k_adafuse<<<NODEW_B, 256, 0, stream>>>(rp, t_csr, (const uint4*)hgig,
                                           (const uint2*)inte_bf, (const uint2*)ebA,
                                           eA, eB, acc, (uint2*)ebB);
    float* t = eA; eA = eB; eB = t;
    unsigned short* tb = ebA; ebA = ebB; ebB = tb;
  }
}

// Round 2
// 1017.673 us; speedup vs baseline: 1.4150x; 1.0487x over previous
//
#include <hip/hip_runtime.h>
#include <hip/hip_bf16.h>

#define N_USERS   50000
#define N_ITEMS   100000
#define N_NODES   150000
#define DIM       64
#define N_INTENTS 128
#define N_EDGES   3000000
#define PSHIFT    9                         // 512 rows per partition
#define PROWS     (1 << PSHIFT)
#define NPART     ((N_NODES + PROWS - 1) >> PSHIFT)   // 293
#define CHUNK     16384                     // edges per binning block
#define NCHB      ((N_EDGES + CHUNK - 1) / CHUNK)     // 184

typedef __attribute__((ext_vector_type(8))) short short8v;  // 8 bf16 (4 VGPRs)
typedef __attribute__((ext_vector_type(4))) float f32x4;

static __device__ __forceinline__ float wsum64(float v){
#pragma unroll
  for (int m = 32; m >= 1; m >>= 1) v += __shfl_xor(v, m, 64);
  return v;
}
static __device__ __forceinline__ float wmax64(float v){
#pragma unroll
  for (int m = 32; m >= 1; m >>= 1) v = fmaxf(v, __shfl_xor(v, m, 64));
  return v;
}

// ---- DPP 16-lane row reduction (full-rate VALU)
template<int CTRL>
static __device__ __forceinline__ float dpp_ror_add(float x){
  int t = __builtin_amdgcn_update_dpp(0, __builtin_bit_cast(int, x),
                                      CTRL, 0xF, 0xF, true);
  return x + __builtin_bit_cast(float, t);
}
static __device__ __forceinline__ float row16_allsum(float x){
  x = dpp_ror_add<0x128>(x);  // row_ror:8
  x = dpp_ror_add<0x124>(x);  // row_ror:4
  x = dpp_ror_add<0x122>(x);  // row_ror:2
  x = dpp_ror_add<0x121>(x);  // row_ror:1
  return x;
}
template<int CTRL>
static __device__ __forceinline__ float dpp_ror_max(float x){
  int t = __builtin_amdgcn_update_dpp(0, __builtin_bit_cast(int, x),
                                      CTRL, 0xF, 0xF, true);
  return fmaxf(x, __builtin_bit_cast(float, t));
}
static __device__ __forceinline__ float row16_allmax(float x){
  x = dpp_ror_max<0x128>(x);
  x = dpp_ror_max<0x124>(x);
  x = dpp_ror_max<0x122>(x);
  x = dpp_ror_max<0x121>(x);
  return x;
}

// bf16 pack/unpack
static __device__ __forceinline__ unsigned short f2bf(float x){
  __hip_bfloat16 h = __float2bfloat16(x);
  return __builtin_bit_cast(unsigned short, h);
}
static __device__ __forceinline__ float bf_lo(unsigned int v){
  return __builtin_bit_cast(float, v << 16);
}
static __device__ __forceinline__ float bf_hi(unsigned int v){
  return __builtin_bit_cast(float, v & 0xFFFF0000u);
}
static __device__ __forceinline__ float bfval(unsigned short h){
  return __builtin_bit_cast(float, (unsigned int)h << 16);
}
// hi/lo bf16 split: x ~= bf(hi) + bf(lo), rel err ~2^-17 (fp32-fidelity for MFMA)
static __device__ __forceinline__ void split2(float x, unsigned short& hi,
                                              unsigned short& lo){
  hi = f2bf(x);
  lo = f2bf(x - bfval(hi));
}

// emb = concat(user_emb, item_emb); acc(=d_out) = emb; embb = bf16(emb)
__global__ void k_init(const float* __restrict__ ue, const float* __restrict__ ie,
                       float* __restrict__ emb, float* __restrict__ acc,
                       unsigned short* __restrict__ embb){
  int i = blockIdx.x * 256 + threadIdx.x;
  if (i >= N_NODES * DIM) return;
  float v = (i < N_USERS * DIM) ? ue[i] : ie[i - N_USERS * DIM];
  emb[i] = v; acc[i] = v; embb[i] = f2bf(v);
}

__global__ void k_deg(const int* __restrict__ h, int* __restrict__ deg){
  int e = blockIdx.x * 256 + threadIdx.x;
  if (e < N_EDGES) atomicAdd(&deg[h[e]], 1);
}

__global__ void k_scan1(const int* __restrict__ deg, int* __restrict__ tmp,
                        int* __restrict__ aux){
  __shared__ int s[256];
  int t = threadIdx.x, i = blockIdx.x * 256 + t;
  int v = (i < N_NODES) ? deg[i] : 0;
  s[t] = v; __syncthreads();
  for (int off = 1; off < 256; off <<= 1){
    int x = (t >= off) ? s[t - off] : 0;
    __syncthreads();
    s[t] += x;
    __syncthreads();
  }
  if (i < N_NODES) tmp[i] = s[t];
  if (t == 255) aux[blockIdx.x] = s[255];
}

__global__ __launch_bounds__(1024) void k_scan2(int* __restrict__ aux, int n){
  __shared__ int s[1024];
  int t = threadIdx.x;
  int v = (t < n) ? aux[t] : 0;
  s[t] = v; __syncthreads();
  for (int off = 1; off < 1024; off <<= 1){
    int x = (t >= off) ? s[t - off] : 0;
    __syncthreads();
    s[t] += x;
    __syncthreads();
  }
  if (t < n) aux[t] = s[t] - v;   // exclusive
}

__global__ void k_rowptr(const int* __restrict__ tmp, const int* __restrict__ deg,
                         const int* __restrict__ aux, int* __restrict__ rp,
                         float* __restrict__ dis, int* __restrict__ gcur){
  int i = blockIdx.x * 256 + threadIdx.x;
  if (i < N_NODES){
    int v = aux[i >> 8] + tmp[i] - deg[i];
    rp[i] = v;
    int d = deg[i];
    dis[i] = (d > 0) ? (1.f / sqrtf((float)d)) : 0.f;
    if ((i & (PROWS - 1)) == 0) gcur[i >> PSHIFT] = v;  // partition append cursor
  }
  if (i == 0) rp[N_NODES] = N_EDGES;
}

// Counting-sort pass 1: per-block LDS histogram over 293 partitions, ONE
// global reservation per (block,partition), then scatter into block-exclusive
// contiguous runs.
__global__ __launch_bounds__(256) void k_part1(const int* __restrict__ h,
                                               const int* __restrict__ t,
                                               int* __restrict__ gcur,
                                               unsigned int* __restrict__ stg){
  __shared__ int hist[NPART];
  __shared__ int base[NPART];
  __shared__ int cnt2[NPART];
  int tid = threadIdx.x;
  int s = blockIdx.x * CHUNK;
  int e = min(s + CHUNK, N_EDGES);
  for (int p = tid; p < NPART; p += 256){ hist[p] = 0; cnt2[p] = 0; }
  __syncthreads();
  for (int i = s + tid; i < e; i += 256)
    atomicAdd(&hist[h[i] >> PSHIFT], 1);
  __syncthreads();
  for (int p = tid; p < NPART; p += 256){
    int c = hist[p];
    base[p] = c ? atomicAdd(&gcur[p], c) : 0;
  }
  __syncthreads();
  for (int i = s + tid; i < e; i += 256){
    int hh = h[i];
    int part = hh >> PSHIFT;
    int pos = base[part] + atomicAdd(&cnt2[part], 1);
    stg[pos] = ((unsigned)t[i] << PSHIFT) | (unsigned)(hh & (PROWS - 1));
  }
}

// Counting-sort pass 2: one block per partition.
__global__ __launch_bounds__(256) void k_part2(const int* __restrict__ rp,
                                               const unsigned int* __restrict__ stg,
                                               int* __restrict__ t_csr){
  __shared__ int cur[PROWS];
  int b = blockIdx.x, tid = threadIdx.x;
  int row0 = b << PSHIFT;
  int rows = min(PROWS, N_NODES - row0);
  for (int i = tid; i < rows; i += 256) cur[i] = rp[row0 + i];
  __syncthreads();
  int s = rp[row0], e = rp[row0 + rows];
  for (int i = s + tid; i < e; i += 256){
    unsigned int v = stg[i];
    int pos = atomicAdd(&cur[v & (PROWS - 1)], 1);
    t_csr[pos] = (int)(v >> PSHIFT);
  }
}

// gnn[n] = dis[n] * sum_e dis[t_e] * emb[t_e]. 8 edges in flight per wave,
// 16B bf16 loads; L2-normalized row -> contiguous bf16 hgA.
__global__ void k_spmm_gnn(const int* __restrict__ rp, const int* __restrict__ t_csr,
                           const float* __restrict__ dis,
                           const unsigned short* __restrict__ embb,
                           float* __restrict__ gnn, unsigned short* __restrict__ hgA){
  int w = (blockIdx.x * 256 + threadIdx.x) >> 6;
  int lane = threadIdx.x & 63;
  if (w >= N_NODES) return;
  int slot = lane >> 3, sub = lane & 7;      // 8 slots x 8 dims
  int s = rp[w], e = rp[w + 1];
  float a0=0.f,a1=0.f,a2=0.f,a3=0.f,a4=0.f,a5=0.f,a6=0.f,a7=0.f;
  for (int i = s + slot; i < e; i += 8){
    int t = t_csr[i];
    float wt = dis[t];
    uint4 ev = *(const uint4*)(embb + (size_t)t * 64 + 8 * sub);
    a0 = fmaf(wt, bf_lo(ev.x), a0); a1 = fmaf(wt, bf_hi(ev.x), a1);
    a2 = fmaf(wt, bf_lo(ev.y), a2); a3 = fmaf(wt, bf_hi(ev.y), a3);
    a4 = fmaf(wt, bf_lo(ev.z), a4); a5 = fmaf(wt, bf_hi(ev.z), a5);
    a6 = fmaf(wt, bf_lo(ev.w), a6); a7 = fmaf(wt, bf_hi(ev.w), a7);
  }
#pragma unroll
  for (int m = 8; m <= 32; m <<= 1){
    a0 += __shfl_xor(a0, m, 64); a1 += __shfl_xor(a1, m, 64);
    a2 += __shfl_xor(a2, m, 64); a3 += __shfl_xor(a3, m, 64);
    a4 += __shfl_xor(a4, m, 64); a5 += __shfl_xor(a5, m, 64);
    a6 += __shfl_xor(a6, m, 64); a7 += __shfl_xor(a7, m, 64);
  }
  float dw = dis[w];
  float g0 = dw*a0, g1 = dw*a1, g2 = dw*a2, g3 = dw*a3;
  float g4 = dw*a4, g5 = dw*a5, g6 = dw*a6, g7 = dw*a7;
  float sq = g0*g0 + g1*g1 + g2*g2 + g3*g3 + g4*g4 + g5*g5 + g6*g6 + g7*g7;
#pragma unroll
  for (int m = 1; m <= 4; m <<= 1) sq += __shfl_xor(sq, m, 64);
  float invn = 1.f / fmaxf(sqrtf(sq), 1e-8f);
  if (slot == 0){
    float4 v0 = make_float4(g0, g1, g2, g3);
    float4 v1 = make_float4(g4, g5, g6, g7);
    ((float4*)gnn)[w * 16 + 2 * sub]     = v0;
    ((float4*)gnn)[w * 16 + 2 * sub + 1] = v1;
    uint4 ob;
    ob.x = (unsigned)f2bf(g0*invn) | ((unsigned)f2bf(g1*invn) << 16);
    ob.y = (unsigned)f2bf(g2*invn) | ((unsigned)f2bf(g3*invn) << 16);
    ob.z = (unsigned)f2bf(g4*invn) | ((unsigned)f2bf(g5*invn) << 16);
    ob.w = (unsigned)f2bf(g6*invn) | ((unsigned)f2bf(g7*invn) << 16);
    *(uint4*)(hgA + (size_t)w * 64 + 8 * sub) = ob;
  }
}

// ---------------------------------------------------------------------------
// One-shot W preparation for the MFMA intent kernel.
// Per W (user=block0, item=block1), seg layout in shorts:
//   [0,8192)      w1 B-frags hi: frag f=nt*2+ks, lane, e -> W[8*(l>>4)+e+32*ks][16*nt+(l&15)]
//   [8192,16384)  w1 B-frags lo
//   [16384,24576) W row-major bf16 hi  (B-frags of W^T read contiguously from here)
//   [24576,32768) W row-major bf16 lo
// ---------------------------------------------------------------------------
__global__ void k_wprep(const float* __restrict__ wu, const float* __restrict__ wi,
                        unsigned short* __restrict__ wbuf){
  const float* W = blockIdx.x ? wi : wu;
  unsigned short* seg = wbuf + blockIdx.x * 32768;
  int tid = threadIdx.x;
  for (int i = tid; i < DIM * N_INTENTS; i += 256){
    unsigned short h, l; split2(W[i], h, l);
    seg[16384 + i] = h; seg[24576 + i] = l;
  }
  for (int idx = tid; idx < 16 * 64; idx += 256){
    int f = idx >> 6, lane = idx & 63;
    int nt = f >> 1, ks = f & 1, g = lane >> 4, c = lane & 15;
    int in = 16 * nt + c;
#pragma unroll
    for (int e = 0; e < 8; e++){
      int d = 8 * g + e + 32 * ks;
      unsigned short h, l; split2(W[d * N_INTENTS + in], h, l);
      seg[f * 512 + lane * 8 + e] = h;
      seg[8192 + f * 512 + lane * 8 + e] = l;
    }
  }
}

// ---------------------------------------------------------------------------
// MFMA intent kernel: out = softmax(emb @ W) @ W^T, bf16 out + L2-norm into
// contiguous bf16 hgB. One 16-node tile per wave; no barriers.
// mfma_f32_16x16x32_bf16 layouts: A[m=l&15][k=8*(l>>4)+e],
// B[k=8*(l>>4)+e][n=l&15], D[m=4*(l>>4)+r][n=l&15].
// ---------------------------------------------------------------------------
__global__ __launch_bounds__(256) void k_intent_mfma(
    const unsigned short* __restrict__ wseg, const float* __restrict__ emb,
    unsigned short* __restrict__ out_bf, unsigned short* __restrict__ hgB,
    int base_node, int count){
  __shared__ __align__(16) unsigned int Pl[4][2048];   // 8KB per wave: P hi|lo packed
  int wid = threadIdx.x >> 6, lane = threadIdx.x & 63;
  int tile = blockIdx.x * 4 + wid;
  if (tile * 16 >= count) return;
  int g = lane >> 4, c = lane & 15;

  // ---- A-frags of E (hi/lo), node row = tile*16 + c, dims 8g..8g+7 (+32 for ks=1)
  const float4* erow = (const float4*)(emb + (size_t)(base_node + tile * 16 + c) * DIM);
  float4 ea0 = erow[2 * g],     eb0 = erow[2 * g + 1];
  float4 ea1 = erow[8 + 2 * g], eb1 = erow[9 + 2 * g];
  short8v ehi[2], elo[2];
  {
    float xs[16] = {ea0.x, ea0.y, ea0.z, ea0.w, eb0.x, eb0.y, eb0.z, eb0.w,
                    ea1.x, ea1.y, ea1.z, ea1.w, eb1.x, eb1.y, eb1.z, eb1.w};
#pragma unroll
    for (int ksi = 0; ksi < 2; ksi++)
#pragma unroll
      for (int e = 0; e < 8; e++){
        unsigned short h, l; split2(xs[ksi * 8 + e], h, l);
        ehi[ksi][e] = (short)h; elo[ksi][e] = (short)l;
      }
  }

  // ---- matmul1: L = E @ W  (8 n-tiles of 16 intents, K=64 in 2 steps)
  const uint4* w1hi = (const uint4*)wseg;
  const uint4* w1lo = (const uint4*)(wseg + 8192);
  f32x4 acc1[8];
#pragma unroll
  for (int nt = 0; nt < 8; nt++){
    f32x4 a = {0.f, 0.f, 0.f, 0.f};
#pragma unroll
    for (int ks = 0; ks < 2; ks++){
      short8v wh = __builtin_bit_cast(short8v, w1hi[(nt * 2 + ks) * 64 + lane]);
      short8v wl = __builtin_bit_cast(short8v, w1lo[(nt * 2 + ks) * 64 + lane]);
      a = __builtin_amdgcn_mfma_f32_16x16x32_bf16(ehi[ks], wh, a, 0, 0, 0);
      a = __builtin_amdgcn_mfma_f32_16x16x32_bf16(elo[ks], wh, a, 0, 0, 0);
      a = __builtin_amdgcn_mfma_f32_16x16x32_bf16(ehi[ks], wl, a, 0, 0, 0);
    }
    acc1[nt] = a;
  }

  // ---- softmax per node (row r of D = node 4g+r). Normalized P packed hi|lo
  // into wave-private LDS, XOR-swizzled for conflict-free frag reads.
  unsigned int* pw = &Pl[wid][0];
#pragma unroll
  for (int r = 0; r < 4; r++){
    float m = acc1[0][r];
#pragma unroll
    for (int nt = 1; nt < 8; nt++) m = fmaxf(m, acc1[nt][r]);
    m = row16_allmax(m);
    float p[8];
    float s = 0.f;
#pragma unroll
    for (int nt = 0; nt < 8; nt++){ p[nt] = __expf(acc1[nt][r] - m); s += p[nt]; }
    s = row16_allsum(s);
    float inv = 1.f / s;
    int node = 4 * g + r;
    int swz = (node & 7) << 2;
    int base = node * 128 + c;
#pragma unroll
    for (int nt = 0; nt < 8; nt++){
      float v = p[nt] * inv;
      unsigned short h, l; split2(v, h, l);
      pw[(base + 16 * nt) ^ swz] = (unsigned int)h | ((unsigned int)l << 16);
    }
  }

  // ---- A-frags of P for matmul2: node = c, intents 8g..8g+7 (+32*ks)
  const uint4* pr = (const uint4*)pw;
  short8v phf[4], plf[4];
  int sw = (c & 7) << 2;
#pragma unroll
  for (int ks = 0; ks < 4; ks++){
    int i0 = c * 128 + 8 * g + 32 * ks;
    uint4 ra = pr[(i0 ^ sw) >> 2];
    uint4 rb = pr[((i0 + 4) ^ sw) >> 2];
    unsigned int q[8] = {ra.x, ra.y, ra.z, ra.w, rb.x, rb.y, rb.z, rb.w};
#pragma unroll
    for (int e = 0; e < 8; e++){
      phf[ks][e] = (short)(q[e] & 0xFFFFu);
      plf[ks][e] = (short)(q[e] >> 16);
    }
  }

  // ---- matmul2: O = P @ W^T. B-frags of W^T are contiguous rows of
  // row-major bf16 W: row = 16*nt + c, cols 8g..8g+7 (+32*ks).
  const uint4* w2hi = (const uint4*)(wseg + 16384);
  const uint4* w2lo = (const uint4*)(wseg + 24576);
  f32x4 acc2[4];
#pragma unroll
  for (int nt = 0; nt < 4; nt++){
    f32x4 a = {0.f, 0.f, 0.f, 0.f};
#pragma unroll
    for (int ks = 0; ks < 4; ks++){
      int fi = (16 * nt + c) * 16 + ks * 4 + g;
      short8v wh = __builtin_bit_cast(short8v, w2hi[fi]);
      short8v wl = __builtin_bit_cast(short8v, w2lo[fi]);
      a = __builtin_amdgcn_mfma_f32_16x16x32_bf16(phf[ks], wh, a, 0, 0, 0);
      a = __builtin_amdgcn_mfma_f32_16x16x32_bf16(plf[ks], wh, a, 0, 0, 0);
      a = __builtin_amdgcn_mfma_f32_16x16x32_bf16(phf[ks], wl, a, 0, 0, 0);
    }
    acc2[nt] = a;
  }

  // ---- outputs: D[m=4g+r][n=c] -> node 4g+r, dim 16*nt + c.
#pragma unroll
  for (int r = 0; r < 4; r++){
    float sq = 0.f;
#pragma unroll
    for (int nt = 0; nt < 4; nt++) sq = fmaf(acc2[nt][r], acc2[nt][r], sq);
    sq = row16_allsum(sq);
    float invn = 1.f / fmaxf(sqrtf(sq), 1e-8f);
    size_t gbase = (size_t)(base_node + tile * 16 + 4 * g + r) * DIM + c;
#pragma unroll
    for (int nt = 0; nt < 4; nt++){
      float v = acc2[nt][r];
      out_bf[gbase + 16 * nt] = f2bf(v);
      hgB[gbase + 16 * nt] = f2bf(v * invn);
    }
  }
}

// ---------------------------------------------------------------------------
// Fused adaptive passes + residual + acc + bf16 emb for next layer.
// Per 16-edge batch: gathered neighbor rows (16x64 bf16) form MFMA A-frags
// directly (no unpack); B = broadcast hg[w] (hoisted). D[m=4g+r][n=c] gives
// lane (g,c) the cosines of edges 4g+r -> alphas live exactly where the
// emb-accumulation needs them (edges 4g+r, dims 4c..4c+3). Tail edges are
// clamped to e-1 with alpha=0 (duplicate addresses coalesce: no extra traffic).
// ---------------------------------------------------------------------------
__global__ void k_adafuse(const int* __restrict__ rp, const int* __restrict__ t_csr,
                          const unsigned short* __restrict__ hgA,
                          const unsigned short* __restrict__ hgB,
                          const uint2* __restrict__ inte_bf2,
                          const unsigned short* __restrict__ embb,
                          const float* __restrict__ emb,
                          float* __restrict__ gnn_io, float* __restrict__ acc,
                          uint2* __restrict__ embb_next2){
  int w = (blockIdx.x * 256 + threadIdx.x) >> 6;
  int lane = threadIdx.x & 63;
  if (w >= N_NODES) return;
  int g = lane >> 4, c = lane & 15;
  // B-frags: hg[w] broadcast (B[k=8g+e][n]=hg_w[8g+e] for all n), hoisted
  const unsigned short* wa = hgA + (size_t)w * 64;
  const unsigned short* wb = hgB + (size_t)w * 64;
  short8v bA0 = *(const short8v*)(wa + 8 * g);
  short8v bA1 = *(const short8v*)(wa + 8 * g + 32);
  short8v bB0 = *(const short8v*)(wb + 8 * g);
  short8v bB1 = *(const short8v*)(wb + 8 * g + 32);
  int s = rp[w], e = rp[w + 1];
  float4 s1 = make_float4(0.f, 0.f, 0.f, 0.f);
  float4 s2 = make_float4(0.f, 0.f, 0.f, 0.f);
  float r1 = 0.f, r2 = 0.f;
  for (int i = s; i < e; i += 16){
    int ia = i + c; if (ia >= e) ia = e - 1;
    int t = t_csr[ia];
    const unsigned short* ra = hgA + (size_t)t * 64;
    const unsigned short* rb = hgB + (size_t)t * 64;
    short8v aA0 = *(const short8v*)(ra + 8 * g);
    short8v aA1 = *(const short8v*)(ra + 8 * g + 32);
    short8v aB0 = *(const short8v*)(rb + 8 * g);
    short8v aB1 = *(const short8v*)(rb + 8 * g + 32);
    f32x4 p = {0.f, 0.f, 0.f, 0.f};
    f32x4 q = {0.f, 0.f, 0.f, 0.f};
    p = __builtin_amdgcn_mfma_f32_16x16x32_bf16(aA0, bA0, p, 0, 0, 0);
    p = __builtin_amdgcn_mfma_f32_16x16x32_bf16(aA1, bA1, p, 0, 0, 0);
    q = __builtin_amdgcn_mfma_f32_16x16x32_bf16(aB0, bB0, q, 0, 0, 0);
    q = __builtin_amdgcn_mfma_f32_16x16x32_bf16(aB1, bB1, q, 0, 0, 0);
#pragma unroll
    for (int r = 0; r < 4; r++){
      int ei = i + 4 * g + r;
      bool valid = ei < e;
      float a1v = valid ? fmaf(p[r], 0.5f, 0.5f) : 0.f;
      float a2v = valid ? fmaf(q[r], 0.5f, 0.5f) : 0.f;
      r1 += a1v; r2 += a2v;
      int tt = t_csr[valid ? ei : (e - 1)];
      uint2 ev = *(const uint2*)(embb + (size_t)tt * 64 + 4 * c);
      float v0 = bf_lo(ev.x), v1 = bf_hi(ev.x), v2 = bf_lo(ev.y), v3 = bf_hi(ev.y);
      s1.x = fmaf(a1v, v0, s1.x); s1.y = fmaf(a1v, v1, s1.y);
      s1.z = fmaf(a1v, v2, s1.z); s1.w = fmaf(a1v, v3, s1.w);
      s2.x = fmaf(a2v, v0, s2.x); s2.y = fmaf(a2v, v1, s2.y);
      s2.z = fmaf(a2v, v2, s2.z); s2.w = fmaf(a2v, v3, s2.w);
    }
  }
#pragma unroll
  for (int m = 16; m <= 32; m <<= 1){
    s1.x += __shfl_xor(s1.x, m, 64); s1.y += __shfl_xor(s1.y, m, 64);
    s1.z += __shfl_xor(s1.z, m, 64); s1.w += __shfl_xor(s1.w, m, 64);
    s2.x += __shfl_xor(s2.x, m, 64); s2.y += __shfl_xor(s2.y, m, 64);
    s2.z += __shfl_xor(s2.z, m, 64); s2.w += __shfl_xor(s2.w, m, 64);
    r1   += __shfl_xor(r1,   m, 64); r2   += __shfl_xor(r2,   m, 64);
  }
  float d1 = (r1 > 0.f) ? 1.f / r1 : 0.f;
  float d2 = (r2 > 0.f) ? 1.f / r2 : 0.f;
  if (g == 0){
    int idx4 = w * 16 + c;
    float4 gg = ((float4*)gnn_io)[idx4];
    uint2 it = inte_bf2[idx4];
    float4 em = ((const float4*)emb)[idx4];
    float4 nv;
    nv.x = gg.x + bf_lo(it.x) + em.x + d1 * s1.x + d2 * s2.x;
    nv.y = gg.y + bf_hi(it.x) + em.y + d1 * s1.y + d2 * s2.y;
    nv.z = gg.z + bf_lo(it.y) + em.z + d1 * s1.z + d2 * s2.z;
    nv.w = gg.w + bf_hi(it.y) + em.w + d1 * s1.w + d2 * s2.w;
    ((float4*)gnn_io)[idx4] = nv;
    float4 ac = ((float4*)acc)[idx4];
    ac.x += nv.x; ac.y += nv.y; ac.z += nv.z; ac.w += nv.w;
    ((float4*)acc)[idx4] = ac;
    uint2 ob;
    ob.x = (unsigned)f2bf(nv.x) | ((unsigned)f2bf(nv.y) << 16);
    ob.y = (unsigned)f2bf(nv.z) | ((unsigned)f2bf(nv.w) << 16);
    embb_next2[idx4] = ob;   // bf16 emb for next layer (other buffer: no race)
  }
}

extern "C" void kernel_launch(void* const* d_in, const int* in_sizes, int n_in,
                              void* d_out, int out_size, void* d_ws, size_t ws_size,
                              hipStream_t stream){
  const float* ue = (const float*)d_in[0];
  const float* ie = (const float*)d_in[1];
  const float* wu = (const float*)d_in[2];
  const float* wi = (const float*)d_in[3];
  const int* all_h = (const int*)d_in[4];
  const int* all_t = (const int*)d_in[5];
  float* acc = (float*)d_out;

  char* p = (char*)d_ws;
  auto take = [&](size_t bytes)->char*{
    char* r = p; p += (bytes + 255) & ~size_t(255); return r;
  };
  float*  embA  = (float*)take(sizeof(float) * N_NODES * DIM);
  float*  embB  = (float*)take(sizeof(float) * N_NODES * DIM);
  unsigned short* hgA = (unsigned short*)take(sizeof(short) * N_NODES * DIM);
  unsigned short* hgB = (unsigned short*)take(sizeof(short) * N_NODES * DIM);
  unsigned short* inte_bf = (unsigned short*)take(sizeof(short) * N_NODES * DIM);
  unsigned short* embbA   = (unsigned short*)take(sizeof(short) * N_NODES * DIM);
  unsigned short* embbB   = (unsigned short*)take(sizeof(short) * N_NODES * DIM);
  unsigned short* wbuf    = (unsigned short*)take(sizeof(short) * 2 * 32768);
  int*    t_csr = (int*)take(sizeof(int) * N_EDGES);
  float*  dis   = (float*)take(sizeof(float) * N_NODES);
  int*    deg   = (int*)take(sizeof(int) * N_NODES);
  int*    tmp   = (int*)take(sizeof(int) * N_NODES);
  int*    aux   = (int*)take(sizeof(int) * 1024);
  int*    rp    = (int*)take(sizeof(int) * (N_NODES + 1));
  int*    gcur  = (int*)take(sizeof(int) * NPART);
  if ((size_t)(p - (char*)d_ws) > ws_size) return;
  // staging (12 MB) aliases hgA (19.2 MB): only live before spmm writes hgA
  unsigned int* stg = (unsigned int*)hgA;

  const int ELEM_B  = (N_NODES * DIM + 255) / 256;
  const int NODEW_B = (N_NODES * 64 + 255) / 256;
  const int EDGE_B  = (N_EDGES + 255) / 256;
  const int NODE_B  = (N_NODES + 255) / 256;

  hipMemsetAsync(deg, 0, sizeof(int) * N_NODES, stream);
  k_init<<<ELEM_B, 256, 0, stream>>>(ue, ie, embA, acc, embbA);
  k_wprep<<<2, 256, 0, stream>>>(wu, wi, wbuf);
  k_deg<<<EDGE_B, 256, 0, stream>>>(all_h, deg);
  k_scan1<<<NODE_B, 256, 0, stream>>>(deg, tmp, aux);
  k_scan2<<<1, 1024, 0, stream>>>(aux, NODE_B);
  k_rowptr<<<NODE_B, 256, 0, stream>>>(tmp, deg, aux, rp, dis, gcur);
  k_part1<<<NCHB, 256, 0, stream>>>(all_h, all_t, gcur, stg);
  k_part2<<<NPART, 256, 0, stream>>>(rp, stg, t_csr);

  const int UT_B = ((N_USERS / 16) + 3) / 4;   // user tiles -> blocks
  const int IT_B = ((N_ITEMS / 16) + 3) / 4;   // item tiles -> blocks

  float* eA = embA;
  float* eB = embB;
  unsigned short* ebA = embbA;  // bf16 of current emb
  unsigned short* ebB = embbB;
  for (int layer = 0; layer < 2; layer++){
    k_spmm_gnn<<<NODEW_B, 256, 0, stream>>>(rp, t_csr, dis, ebA, eB, hgA);
    k_intent_mfma<<<UT_B, 256, 0, stream>>>(wbuf, eA, inte_bf, hgB, 0, N_USERS);
    k_intent_mfma<<<IT_B, 256, 0, stream>>>(wbuf + 32768, eA, inte_bf, hgB,
                                            N_USERS, N_ITEMS);
    k_adafuse<<<NODEW_B, 256, 0, stream>>>(rp, t_csr, hgA, hgB,
                                           (const uint2*)inte_bf, ebA,
                                           eA, eB, acc, (uint2*)ebB);
    float* t = eA; eA = eB; eB = t;
    unsigned short* tb = ebA; ebA = ebB; ebB = tb;
  }
}